// Round 10
// baseline (188.428 us; speedup 1.0000x reference)
//
#include <hip/hip_runtime.h>

// SynthMorphLoss: soft-dice over int32 label maps + diffusion regularizer.
// B=1, D=160, H=192, W=224, 26 classes (class 0 ignored in dice mean).
// R16: remove the init dispatch (3 -> 2 dispatches). Evidence: total ==
// fused + ~117us fixed across 6 runs; R13 showed one tiny dispatch ~ 11.8us
// of that. Init exists only to zero atomically-accumulated bins; switch to
// PER-BLOCK PRIVATE SLOTS (plain stores, nothing needs pre-zeroing):
//   hist: 105 blocks x 512thr x 32 int4/map -> slot[105][858] (360 KB)
//   diff: 192 blocks -> 3 doubles each (R12 dual-chain body verbatim)
//   finalize: 1024 thr; bins[t] = sum over 105 slots (coalesced), diff
//   partials reduced by 3 waves; then the proven dice epilogue from LDS.
// NOT the R13 done-ticket (that throttled block retire, +46us): the
// dispatch boundary stays as the only sync; only its payload changes.
// ws_size unknown -> host branch: slotted path needs ~365KB, else exact
// R15 fallback (init + atomic bins + tiny finalize). Either path correct.

namespace {
constexpr int NC    = 26;
constexpr int Dd    = 160, Hh = 192, Ww = 224;
constexpr int W4    = Ww / 4;                 // 56 float4 per row
constexpr int PL4   = Hh * W4;                // 10752 float4 per (c,d) plane
constexpr int N4L   = Dd * Hh * Ww / 4;       // 1,720,320 int4 per label map
constexpr int JSTRIDE = 33;                   // joint-hist row stride
constexpr int NBINS   = NC * JSTRIDE;         // 858
constexpr int TPB     = 512;                  // 8 waves per block
constexpr int WPB     = TPB / 64;             // 8
// slotted hist: 105 blocks x 512 thr x 32 int4 (105*512*32 == N4L exact)
constexpr int HS_BLOCKS = 105;
constexpr int HTS       = HS_BLOCKS * TPB;         // 53760
// fallback hist (R15-proven): 420 blocks x 512 thr x 8 int4
constexpr int HF_BLOCKS = 420;
constexpr int HTF       = HF_BLOCKS * TPB;         // 215040
// diff: tile = (c, 6-row h-slab, 5-plane d-chunk); 3072 tiles; dual-chain.
constexpr int SLAB    = 6;
constexpr int DCH     = 5;
constexpr int NTILES  = 3 * (Dd / DCH) * (Hh / SLAB);  // 3072
constexpr int DIFF_WAVES  = NTILES / 2;                // 1536
constexpr int DIFF_BLOCKS = DIFF_WAVES / WPB;          // 192
constexpr int FS_BLOCKS = DIFF_BLOCKS + HS_BLOCKS;     // 297 (slotted)
constexpr int FF_BLOCKS = DIFF_BLOCKS + HF_BLOCKS;     // 612 (fallback)
// slotted workspace layout
constexpr size_t SLOT_BYTES = (size_t)HS_BLOCKS * NBINS * 4;      // 360,360
constexpr size_t DPART_OFF  = 360448;                             // 8-aligned
constexpr size_t WS_NEEDED  = DPART_OFF + (size_t)DIFF_BLOCKS * 3 * 8; // 365,056
}

// ======================= shared device bodies =======================

#define JACC(A, B)                                   \
    atomicAdd(&h[(A).x * JSTRIDE + (B).x], 1u);      \
    atomicAdd(&h[(A).y * JSTRIDE + (B).y], 1u);      \
    atomicAdd(&h[(A).z * JSTRIDE + (B).z], 1u);      \
    atomicAdd(&h[(A).w * JSTRIDE + (B).w], 1u);

// 8-wide accumulation step at stride HT starting from index b0.
template <int HT>
__device__ __forceinline__ void hist_step8(
        unsigned int* h, const int4* __restrict__ f4,
        const int4* __restrict__ m4, int b0) {
    int4 a0 = f4[b0];
    int4 a1 = f4[b0 + HT];
    int4 a2 = f4[b0 + 2 * HT];
    int4 a3 = f4[b0 + 3 * HT];
    int4 a4 = f4[b0 + 4 * HT];
    int4 a5 = f4[b0 + 5 * HT];
    int4 a6 = f4[b0 + 6 * HT];
    int4 a7 = f4[b0 + 7 * HT];
    int4 b0v = m4[b0];
    int4 b1 = m4[b0 + HT];
    int4 b2 = m4[b0 + 2 * HT];
    int4 b3 = m4[b0 + 3 * HT];
    int4 b4 = m4[b0 + 4 * HT];
    int4 b5 = m4[b0 + 5 * HT];
    int4 b6 = m4[b0 + 6 * HT];
    int4 b7 = m4[b0 + 7 * HT];
    JACC(a0, b0v) JACC(a1, b1) JACC(a2, b2) JACC(a3, b3)
    JACC(a4, b4) JACC(a5, b5) JACC(a6, b6) JACC(a7, b7)
}
#undef JACC

// slotted hist: 32 int4/map, private slot flush (plain stores, no init need)
__device__ __forceinline__ void hist_slot(
        int hb, const int4* __restrict__ f4, const int4* __restrict__ m4,
        unsigned int* __restrict__ slots) {
    __shared__ unsigned int h[NBINS];
    for (int i = threadIdx.x; i < NBINS; i += TPB) h[i] = 0u;
    __syncthreads();
    const int g = hb * TPB + threadIdx.x;
    #pragma unroll
    for (int it = 0; it < 4; ++it)
        hist_step8<HTS>(h, f4, m4, g + it * 8 * HTS);
    __syncthreads();
    unsigned int* slot = slots + (size_t)hb * NBINS;
    for (int i = threadIdx.x; i < NBINS; i += TPB) slot[i] = h[i];
}

// fallback hist: R15-proven (8 int4/map, atomic flush into zeroed bins)
__device__ __forceinline__ void hist_atomic(
        int hb, const int4* __restrict__ f4, const int4* __restrict__ m4,
        unsigned int* __restrict__ gj) {
    __shared__ unsigned int h[NBINS];
    for (int i = threadIdx.x; i < NBINS; i += TPB) h[i] = 0u;
    __syncthreads();
    const int g = hb * TPB + threadIdx.x;
    hist_step8<HTF>(h, f4, m4, g);
    __syncthreads();
    for (int i = threadIdx.x; i < NBINS; i += TPB) {
        unsigned int v = h[i];
        if (v) atomicAdd(&gj[i], v);
    }
}

// diff: TWO independent z-carry chains per wave (R12 verbatim).
// SLOT: thread0 writes per-block partial; else atomicAdd into gs.
template <bool SLOT>
__device__ __forceinline__ void diff_path(
        int db, const float4* __restrict__ v4, double* __restrict__ gs) {
    const int lane = threadIdx.x & 63;
    const int wid  = threadIdx.x >> 6;
    const int w    = db * WPB + wid;          // 0..1535
    const bool al  = (lane < W4);
    const int  l   = al ? lane : (W4 - 1);    // clamp inactive lanes

    const int tA = w;
    const int cA = tA >> 10, remA = tA & 1023;
    const int d0A = (remA >> 5) * DCH;
    const int h0A = (remA & 31) * SLAB;
    const bool hvA = (h0A + SLAB < Hh);
    const int hOffA = (hvA ? SLAB : SLAB - 1) * W4;
    size_t curA = ((size_t)(cA * Dd + d0A) * Hh + h0A) * W4 + l;
    const int tB = w + DIFF_WAVES;
    const int cB = tB >> 10, remB = tB & 1023;
    const int d0B = (remB >> 5) * DCH;
    const int h0B = (remB & 31) * SLAB;
    const bool hvB = (h0B + SLAB < Hh);
    const int hOffB = (hvB ? SLAB : SLAB - 1) * W4;
    size_t curB = ((size_t)(cB * Dd + d0B) * Hh + h0B) * W4 + l;

    float4 pA0 = v4[curA];
    float4 pA1 = v4[curA + W4];
    float4 pA2 = v4[curA + 2 * W4];
    float4 pA3 = v4[curA + 3 * W4];
    float4 pA4 = v4[curA + 4 * W4];
    float4 pA5 = v4[curA + 5 * W4];
    float4 pB0 = v4[curB];
    float4 pB1 = v4[curB + W4];
    float4 pB2 = v4[curB + 2 * W4];
    float4 pB3 = v4[curB + 3 * W4];
    float4 pB4 = v4[curB + 4 * W4];
    float4 pB5 = v4[curB + 5 * W4];

    float sx = 0.f, sy = 0.f, sz = 0.f;

#define DX(P)                                                                  \
    {                                                                          \
        float d1 = (P).y - (P).x, d2 = (P).z - (P).y, d3 = (P).w - (P).z;      \
        sx += d1 * d1 + d2 * d2 + d3 * d3;                                     \
        float nx = __shfl_down((P).x, 1);                                      \
        float d4 = nx - (P).w;                                                 \
        sx += (lane < W4 - 1) ? d4 * d4 : 0.f;                                 \
    }
#define DY(A, B)                                                               \
    {                                                                          \
        float e0 = (B).x - (A).x, e1 = (B).y - (A).y;                          \
        float e2 = (B).z - (A).z, e3 = (B).w - (A).w;                          \
        sy += e0 * e0 + e1 * e1 + e2 * e2 + e3 * e3;                           \
    }
#define DZ(A, B)                                                               \
    {                                                                          \
        float e0 = (B).x - (A).x, e1 = (B).y - (A).y;                          \
        float e2 = (B).z - (A).z, e3 = (B).w - (A).w;                          \
        sz += e0 * e0 + e1 * e1 + e2 * e2 + e3 * e3;                           \
    }

    for (int k = 0; k < DCH; ++k) {
        const bool dzvA = (d0A + k < Dd - 1);     // wave-uniform
        const bool dzvB = (d0B + k < Dd - 1);
        float4 hlA = v4[curA + hOffA];
        float4 hlB = v4[curB + hOffB];
        float4 nA0 = pA0, nA1 = pA1, nA2 = pA2, nA3 = pA3, nA4 = pA4, nA5 = pA5;
        if (dzvA) {
            const size_t nb = curA + PL4;
            nA0 = v4[nb];
            nA1 = v4[nb + W4];
            nA2 = v4[nb + 2 * W4];
            nA3 = v4[nb + 3 * W4];
            nA4 = v4[nb + 4 * W4];
            nA5 = v4[nb + 5 * W4];
        }
        float4 nB0 = pB0, nB1 = pB1, nB2 = pB2, nB3 = pB3, nB4 = pB4, nB5 = pB5;
        if (dzvB) {
            const size_t nb = curB + PL4;
            nB0 = v4[nb];
            nB1 = v4[nb + W4];
            nB2 = v4[nb + 2 * W4];
            nB3 = v4[nb + 3 * W4];
            nB4 = v4[nb + 4 * W4];
            nB5 = v4[nb + 5 * W4];
        }

        DX(pA0) DX(pA1) DX(pA2) DX(pA3) DX(pA4) DX(pA5)
        DY(pA0, pA1) DY(pA1, pA2) DY(pA2, pA3) DY(pA3, pA4) DY(pA4, pA5)
        if (hvA) DY(pA5, hlA)
        if (dzvA) {
            DZ(pA0, nA0) DZ(pA1, nA1) DZ(pA2, nA2)
            DZ(pA3, nA3) DZ(pA4, nA4) DZ(pA5, nA5)
        }
        DX(pB0) DX(pB1) DX(pB2) DX(pB3) DX(pB4) DX(pB5)
        DY(pB0, pB1) DY(pB1, pB2) DY(pB2, pB3) DY(pB3, pB4) DY(pB4, pB5)
        if (hvB) DY(pB5, hlB)
        if (dzvB) {
            DZ(pB0, nB0) DZ(pB1, nB1) DZ(pB2, nB2)
            DZ(pB3, nB3) DZ(pB4, nB4) DZ(pB5, nB5)
        }

        pA0 = nA0; pA1 = nA1; pA2 = nA2; pA3 = nA3; pA4 = nA4; pA5 = nA5;
        pB0 = nB0; pB1 = nB1; pB2 = nB2; pB3 = nB3; pB4 = nB4; pB5 = nB5;
        curA += PL4; curB += PL4;
    }
#undef DX
#undef DY
#undef DZ

    if (!al) { sx = 0.f; sy = 0.f; sz = 0.f; }

    #pragma unroll
    for (int off = 32; off > 0; off >>= 1) {
        sx += __shfl_down(sx, off);
        sy += __shfl_down(sy, off);
        sz += __shfl_down(sz, off);
    }
    __shared__ float px[WPB], py[WPB], pz[WPB];
    if (lane == 0) { px[wid] = sx; py[wid] = sy; pz[wid] = sz; }
    __syncthreads();
    if (threadIdx.x == 0) {
        float tx = 0.f, ty = 0.f, tz = 0.f;
        #pragma unroll
        for (int i = 0; i < WPB; ++i) { tx += px[i]; ty += py[i]; tz += pz[i]; }
        if constexpr (SLOT) {
            gs[db * 3 + 0] = (double)tx;      // private slot: plain stores
            gs[db * 3 + 1] = (double)ty;
            gs[db * 3 + 2] = (double)tz;
        } else {
            atomicAdd(&gs[0], (double)tx);
            atomicAdd(&gs[1], (double)ty);
            atomicAdd(&gs[2], (double)tz);
        }
    }
}

// ======================= kernels: slotted path =======================

__global__ __launch_bounds__(512, 2) void fused_slots_kernel(
        const int4* __restrict__ f4,
        const int4* __restrict__ m4,
        unsigned int* __restrict__ slots,
        const float4* __restrict__ v4,
        double* __restrict__ dparts) {
    if (blockIdx.x < DIFF_BLOCKS) diff_path<true>(blockIdx.x, v4, dparts);
    else                          hist_slot(blockIdx.x - DIFF_BLOCKS, f4, m4, slots);
}

__global__ void finalize_slots_kernel(
        const unsigned int* __restrict__ slots,
        const double* __restrict__ dparts,
        float* __restrict__ out) {
    __shared__ unsigned int bins[NBINS];
    __shared__ double wred[3][3];             // 3 waves x {sx,sy,sz}
    const int t = threadIdx.x;

    // bins[t] = sum over the 105 hist slots (coalesced per slice)
    if (t < NBINS) {
        unsigned int s = 0;
        #pragma unroll 5
        for (int b = 0; b < HS_BLOCKS; ++b) s += slots[(size_t)b * NBINS + t];
        bins[t] = s;
    }
    // diff partials: 192 blocks x 3 doubles, reduced by 3 waves
    double dx = 0.0, dy = 0.0, dz = 0.0;
    if (t < DIFF_BLOCKS) {
        dx = dparts[t * 3 + 0];
        dy = dparts[t * 3 + 1];
        dz = dparts[t * 3 + 2];
    }
    #pragma unroll
    for (int off = 32; off > 0; off >>= 1) {
        dx += __shfl_down(dx, off);
        dy += __shfl_down(dy, off);
        dz += __shfl_down(dz, off);
    }
    const int wv = t >> 6;
    if ((t & 63) == 0 && wv < 3) {
        wred[wv][0] = dx; wred[wv][1] = dy; wred[wv][2] = dz;
    }
    __syncthreads();

    if (t < 64) {                             // dice epilogue from LDS bins
        float term = 0.f;
        if (t >= 1 && t < NC) {
            float fv = 0.f, mv = 0.f;
            #pragma unroll
            for (int m = 0; m < NC; ++m) fv += (float)bins[t * JSTRIDE + m];
            #pragma unroll
            for (int f = 0; f < NC; ++f) mv += (float)bins[f * JSTRIDE + t];
            float iv = (float)bins[t * JSTRIDE + t];
            term = (2.f * iv + 1e-5f) / (fv + mv + 1e-5f);
        }
        #pragma unroll
        for (int off = 32; off > 0; off >>= 1) term += __shfl_down(term, off);
        if (t == 0) {
            double g0 = wred[0][0] + wred[1][0] + wred[2][0];
            double g1 = wred[0][1] + wred[1][1] + wred[2][1];
            double g2 = wred[0][2] + wred[1][2] + wred[2][2];
            float sim = 1.f - term * (1.f / 25.f);
            double mdx = g0 / ((double)3 * Dd * Hh * (Ww - 1));
            double mdy = g1 / ((double)3 * Dd * (Hh - 1) * Ww);
            double mdz = g2 / ((double)3 * (Dd - 1) * Hh * Ww);
            float smooth = (float)((mdx + mdy + mdz) / 3.0);
            out[0] = sim + smooth;
            out[1] = sim;
            out[2] = smooth;
        }
    }
}

// ======================= kernels: R15 fallback =======================

__global__ void init_ws_kernel(unsigned int* __restrict__ joint,
                               double* __restrict__ sums) {
    int i = blockIdx.x * blockDim.x + threadIdx.x;
    if (i < NBINS) joint[i] = 0u;
    if (i < 3)     sums[i]  = 0.0;
}

__global__ __launch_bounds__(512, 2) void fused_kernel(
        const int4* __restrict__ f4,
        const int4* __restrict__ m4,
        unsigned int* __restrict__ gj,
        const float4* __restrict__ v4,
        double* __restrict__ gs) {
    if (blockIdx.x < DIFF_BLOCKS) diff_path<false>(blockIdx.x, v4, gs);
    else                          hist_atomic(blockIdx.x - DIFF_BLOCKS, f4, m4, gj);
}

__global__ void finalize_kernel(const unsigned int* __restrict__ gj,
                                const double* __restrict__ gs,
                                float* __restrict__ out) {
    int lane = threadIdx.x & 63;
    float term = 0.f;
    if (lane >= 1 && lane < NC) {
        float fv = 0.f, mv = 0.f;
        #pragma unroll
        for (int m = 0; m < NC; ++m) fv += (float)gj[lane * JSTRIDE + m];
        #pragma unroll
        for (int f = 0; f < NC; ++f) mv += (float)gj[f * JSTRIDE + lane];
        float iv = (float)gj[lane * JSTRIDE + lane];
        term = (2.f * iv + 1e-5f) / (fv + mv + 1e-5f);
    }
    #pragma unroll
    for (int off = 32; off > 0; off >>= 1) term += __shfl_down(term, off);
    if (threadIdx.x == 0 && blockIdx.x == 0) {
        float sim = 1.f - term * (1.f / 25.f);
        double mdx = gs[0] / ((double)3 * Dd * Hh * (Ww - 1));
        double mdy = gs[1] / ((double)3 * Dd * (Hh - 1) * Ww);
        double mdz = gs[2] / ((double)3 * (Dd - 1) * Hh * Ww);
        float smooth = (float)((mdx + mdy + mdz) / 3.0);
        out[0] = sim + smooth;
        out[1] = sim;
        out[2] = smooth;
    }
}

// ======================= launcher =======================

extern "C" void kernel_launch(void* const* d_in, const int* in_sizes, int n_in,
                              void* d_out, int out_size, void* d_ws, size_t ws_size,
                              hipStream_t stream) {
    const int*   fl = (const int*)d_in[0];
    const int*   ml = (const int*)d_in[1];
    const float* vf = (const float*)d_in[2];
    float* out = (float*)d_out;

    if (ws_size >= WS_NEEDED) {
        // 2-dispatch slotted path: no init needed (private slots, plain stores)
        unsigned int* slots  = (unsigned int*)d_ws;
        double*       dparts = (double*)((char*)d_ws + DPART_OFF);
        fused_slots_kernel<<<FS_BLOCKS, TPB, 0, stream>>>(
            (const int4*)fl, (const int4*)ml, slots, (const float4*)vf, dparts);
        finalize_slots_kernel<<<1, 1024, 0, stream>>>(slots, dparts, out);
    } else {
        // R15-proven 3-dispatch fallback
        unsigned int* joint = (unsigned int*)d_ws;
        double*       sums  = (double*)((char*)d_ws + 3584);
        init_ws_kernel<<<1, 1024, 0, stream>>>(joint, sums);
        fused_kernel<<<FF_BLOCKS, TPB, 0, stream>>>(
            (const int4*)fl, (const int4*)ml, joint, (const float4*)vf, sums);
        finalize_kernel<<<1, 64, 0, stream>>>(joint, sums, out);
    }
}

// Round 11
// 174.509 us; speedup vs baseline: 1.0798x; 1.0798x over previous
//
#include <hip/hip_runtime.h>

// SynthMorphLoss: soft-dice over int32 label maps + diffusion regularizer.
// B=1, D=160, H=192, W=224, 26 classes (class 0 ignored in dice mean).
// R17 == R15/R12 verbatim (session best: fused 57.2us, total 174.7us).
// Session ledger of falsified theories (do not retry):
//  - dispatch-overhead (R10: 402 vs 1608 blocks, identical 60.8us)
//  - flat up-front load cluster (R9: compiler serializes, 84us)
//  - per-wave MLP depth (R12: 2x chains -> only +4%)
//  - done-ticket finalize (R13: +46us, block-retire throttled by fences)
//  - launch_bounds tightening (R14: VGPR spill, WRITE 1.4->60MB, 89us)
//  - init-dispatch removal via private slots (R16: fused +8us from long
//    hist blocks; fixed cost went UP — the ~117us fixed is harness-side,
//    not dispatch-count)
// Standing model (fits all 7 measured rounds): fused dur == lane-bytes /
// ~2.9 TB/s chip request-rate wall. R15 = 168 MB @ 1.22x re-load = 57us.
// Perfect re-load 1.0 bounds remaining kernel-side gain at ~10us, with
// demonstrated ~8us regression variance per structural experiment.

namespace {
constexpr int NC    = 26;
constexpr int Dd    = 160, Hh = 192, Ww = 224;
constexpr int W4    = Ww / 4;                 // 56 float4 per row
constexpr int PL4   = Hh * W4;                // 10752 float4 per (c,d) plane
constexpr int N4L   = Dd * Hh * Ww / 4;       // 1,720,320 int4 per label map
constexpr int JSTRIDE = 33;                   // joint-hist row stride
constexpr int NBINS   = NC * JSTRIDE;         // 858
constexpr int TPB     = 512;                  // 8 waves per block
constexpr int WPB     = TPB / 64;             // 8
// hist: 420 blocks x 512 threads x 8 int4 per map (420*512*8 == N4L exact)
constexpr int HIST_BLOCKS = 420;
constexpr int HT          = HIST_BLOCKS * TPB;     // 215040
// diff: tile = (c, 6-row h-slab, 5-plane d-chunk); 3072 tiles total.
// Each wave owns TWO tiles: w and w + 1536.
constexpr int SLAB    = 6;                    // rows per tile
constexpr int DCH     = 5;                    // d-steps per tile
constexpr int NTILES  = 3 * (Dd / DCH) * (Hh / SLAB);  // 3072
constexpr int DIFF_WAVES  = NTILES / 2;                // 1536
constexpr int DIFF_BLOCKS = DIFF_WAVES / WPB;          // 192
constexpr int FUSED_BLOCKS = DIFF_BLOCKS + HIST_BLOCKS;  // 612
}

__global__ void init_ws_kernel(unsigned int* __restrict__ joint,
                               double* __restrict__ sums) {
    int i = blockIdx.x * blockDim.x + threadIdx.x;
    if (i < NBINS) joint[i] = 0u;
    if (i < 3)     sums[i]  = 0.0;
}

// ---- hist path: same per-thread work as R6-R12 (8 int4 per map) ----
__device__ __forceinline__ void hist_path(
        int hb,
        const int4* __restrict__ f4,
        const int4* __restrict__ m4,
        unsigned int* __restrict__ gj) {
    __shared__ unsigned int h[NBINS];
    for (int i = threadIdx.x; i < NBINS; i += TPB) h[i] = 0u;
    __syncthreads();

    const int g = hb * TPB + threadIdx.x;
    int4 a0 = f4[g];
    int4 a1 = f4[g + HT];
    int4 a2 = f4[g + 2 * HT];
    int4 a3 = f4[g + 3 * HT];
    int4 a4 = f4[g + 4 * HT];
    int4 a5 = f4[g + 5 * HT];
    int4 a6 = f4[g + 6 * HT];
    int4 a7 = f4[g + 7 * HT];
    int4 b0 = m4[g];
    int4 b1 = m4[g + HT];
    int4 b2 = m4[g + 2 * HT];
    int4 b3 = m4[g + 3 * HT];
    int4 b4 = m4[g + 4 * HT];
    int4 b5 = m4[g + 5 * HT];
    int4 b6 = m4[g + 6 * HT];
    int4 b7 = m4[g + 7 * HT];

#define JACC(A, B)                                   \
    atomicAdd(&h[(A).x * JSTRIDE + (B).x], 1u);      \
    atomicAdd(&h[(A).y * JSTRIDE + (B).y], 1u);      \
    atomicAdd(&h[(A).z * JSTRIDE + (B).z], 1u);      \
    atomicAdd(&h[(A).w * JSTRIDE + (B).w], 1u);
    JACC(a0, b0) JACC(a1, b1) JACC(a2, b2) JACC(a3, b3)
    JACC(a4, b4) JACC(a5, b5) JACC(a6, b6) JACC(a7, b7)
#undef JACC

    __syncthreads();
    for (int i = threadIdx.x; i < NBINS; i += TPB) {
        unsigned int v = h[i];
        if (v) atomicAdd(&gj[i], v);
    }
}

// ---- diff path: TWO independent z-carry chains per wave (R12 verbatim) ----
// Tile t: c = t>>10, dchunk = (t&1023)>>5, slab = t&31.
__device__ __forceinline__ void diff_path(
        int db,
        const float4* __restrict__ v4,
        double* __restrict__ gs) {
    const int lane = threadIdx.x & 63;
    const int wid  = threadIdx.x >> 6;
    const int w    = db * WPB + wid;          // 0..1535
    const bool al  = (lane < W4);
    const int  l   = al ? lane : (W4 - 1);    // clamp inactive lanes

    // tile A
    const int tA = w;
    const int cA = tA >> 10, remA = tA & 1023;
    const int d0A = (remA >> 5) * DCH;
    const int h0A = (remA & 31) * SLAB;
    const bool hvA = (h0A + SLAB < Hh);
    const int hOffA = (hvA ? SLAB : SLAB - 1) * W4;
    size_t curA = ((size_t)(cA * Dd + d0A) * Hh + h0A) * W4 + l;
    // tile B
    const int tB = w + DIFF_WAVES;
    const int cB = tB >> 10, remB = tB & 1023;
    const int d0B = (remB >> 5) * DCH;
    const int h0B = (remB & 31) * SLAB;
    const bool hvB = (h0B + SLAB < Hh);
    const int hOffB = (hvB ? SLAB : SLAB - 1) * W4;
    size_t curB = ((size_t)(cB * Dd + d0B) * Hh + h0B) * W4 + l;

    float4 pA0 = v4[curA];
    float4 pA1 = v4[curA + W4];
    float4 pA2 = v4[curA + 2 * W4];
    float4 pA3 = v4[curA + 3 * W4];
    float4 pA4 = v4[curA + 4 * W4];
    float4 pA5 = v4[curA + 5 * W4];
    float4 pB0 = v4[curB];
    float4 pB1 = v4[curB + W4];
    float4 pB2 = v4[curB + 2 * W4];
    float4 pB3 = v4[curB + 3 * W4];
    float4 pB4 = v4[curB + 4 * W4];
    float4 pB5 = v4[curB + 5 * W4];

    float sx = 0.f, sy = 0.f, sz = 0.f;

#define DX(P)                                                                  \
    {                                                                          \
        float d1 = (P).y - (P).x, d2 = (P).z - (P).y, d3 = (P).w - (P).z;      \
        sx += d1 * d1 + d2 * d2 + d3 * d3;                                     \
        float nx = __shfl_down((P).x, 1);                                      \
        float d4 = nx - (P).w;                                                 \
        sx += (lane < W4 - 1) ? d4 * d4 : 0.f;                                 \
    }
#define DY(A, B)                                                               \
    {                                                                          \
        float e0 = (B).x - (A).x, e1 = (B).y - (A).y;                          \
        float e2 = (B).z - (A).z, e3 = (B).w - (A).w;                          \
        sy += e0 * e0 + e1 * e1 + e2 * e2 + e3 * e3;                           \
    }
#define DZ(A, B)                                                               \
    {                                                                          \
        float e0 = (B).x - (A).x, e1 = (B).y - (A).y;                          \
        float e2 = (B).z - (A).z, e3 = (B).w - (A).w;                          \
        sz += e0 * e0 + e1 * e1 + e2 * e2 + e3 * e3;                           \
    }

    for (int k = 0; k < DCH; ++k) {
        const bool dzvA = (d0A + k < Dd - 1);     // wave-uniform
        const bool dzvB = (d0B + k < Dd - 1);
        // issue BOTH halo loads + BOTH next-plane clusters up front
        float4 hlA = v4[curA + hOffA];
        float4 hlB = v4[curB + hOffB];
        float4 nA0 = pA0, nA1 = pA1, nA2 = pA2, nA3 = pA3, nA4 = pA4, nA5 = pA5;
        if (dzvA) {
            const size_t nb = curA + PL4;
            nA0 = v4[nb];
            nA1 = v4[nb + W4];
            nA2 = v4[nb + 2 * W4];
            nA3 = v4[nb + 3 * W4];
            nA4 = v4[nb + 4 * W4];
            nA5 = v4[nb + 5 * W4];
        }
        float4 nB0 = pB0, nB1 = pB1, nB2 = pB2, nB3 = pB3, nB4 = pB4, nB5 = pB5;
        if (dzvB) {
            const size_t nb = curB + PL4;
            nB0 = v4[nb];
            nB1 = v4[nb + W4];
            nB2 = v4[nb + 2 * W4];
            nB3 = v4[nb + 3 * W4];
            nB4 = v4[nb + 4 * W4];
            nB5 = v4[nb + 5 * W4];
        }

        // chain A compute
        DX(pA0) DX(pA1) DX(pA2) DX(pA3) DX(pA4) DX(pA5)
        DY(pA0, pA1) DY(pA1, pA2) DY(pA2, pA3) DY(pA3, pA4) DY(pA4, pA5)
        if (hvA) DY(pA5, hlA)
        if (dzvA) {
            DZ(pA0, nA0) DZ(pA1, nA1) DZ(pA2, nA2)
            DZ(pA3, nA3) DZ(pA4, nA4) DZ(pA5, nA5)
        }
        // chain B compute
        DX(pB0) DX(pB1) DX(pB2) DX(pB3) DX(pB4) DX(pB5)
        DY(pB0, pB1) DY(pB1, pB2) DY(pB2, pB3) DY(pB3, pB4) DY(pB4, pB5)
        if (hvB) DY(pB5, hlB)
        if (dzvB) {
            DZ(pB0, nB0) DZ(pB1, nB1) DZ(pB2, nB2)
            DZ(pB3, nB3) DZ(pB4, nB4) DZ(pB5, nB5)
        }

        pA0 = nA0; pA1 = nA1; pA2 = nA2; pA3 = nA3; pA4 = nA4; pA5 = nA5;
        pB0 = nB0; pB1 = nB1; pB2 = nB2; pB3 = nB3; pB4 = nB4; pB5 = nB5;
        curA += PL4; curB += PL4;
    }
#undef DX
#undef DY
#undef DZ

    if (!al) { sx = 0.f; sy = 0.f; sz = 0.f; }    // clamped lanes: drop dupes

    #pragma unroll
    for (int off = 32; off > 0; off >>= 1) {
        sx += __shfl_down(sx, off);
        sy += __shfl_down(sy, off);
        sz += __shfl_down(sz, off);
    }
    __shared__ float px[WPB], py[WPB], pz[WPB];
    if (lane == 0) { px[wid] = sx; py[wid] = sy; pz[wid] = sz; }
    __syncthreads();
    if (threadIdx.x == 0) {
        float tx = 0.f, ty = 0.f, tz = 0.f;
        #pragma unroll
        for (int i = 0; i < WPB; ++i) { tx += px[i]; ty += py[i]; tz += pz[i]; }
        atomicAdd(&gs[0], (double)tx);
        atomicAdd(&gs[1], (double)ty);
        atomicAdd(&gs[2], (double)tz);
    }
}

// 612 blocks of 512 threads: diff blocks [0,192) first (long-running,
// dual-chain), hist blocks [192,612) behind them (short, fill in as CUs
// free up). launch_bounds(512,2): VGPR cap 256 — dual-chain fits (84), no spill.
__global__ __launch_bounds__(512, 2) void fused_kernel(
        const int4* __restrict__ f4,
        const int4* __restrict__ m4,
        unsigned int* __restrict__ gj,
        const float4* __restrict__ v4,
        double* __restrict__ gs) {
    if (blockIdx.x < DIFF_BLOCKS) diff_path(blockIdx.x, v4, gs);
    else                          hist_path(blockIdx.x - DIFF_BLOCKS, f4, m4, gj);
}

__global__ void finalize_kernel(const unsigned int* __restrict__ gj,
                                const double* __restrict__ gs,
                                float* __restrict__ out) {
    int lane = threadIdx.x & 63;
    float term = 0.f;
    if (lane >= 1 && lane < NC) {
        float fv = 0.f, mv = 0.f;
        #pragma unroll
        for (int m = 0; m < NC; ++m) fv += (float)gj[lane * JSTRIDE + m];
        #pragma unroll
        for (int f = 0; f < NC; ++f) mv += (float)gj[f * JSTRIDE + lane];
        float iv = (float)gj[lane * JSTRIDE + lane];
        term = (2.f * iv + 1e-5f) / (fv + mv + 1e-5f);
    }
    #pragma unroll
    for (int off = 32; off > 0; off >>= 1) term += __shfl_down(term, off);
    if (threadIdx.x == 0 && blockIdx.x == 0) {
        float sim = 1.f - term * (1.f / 25.f);
        double mdx = gs[0] / ((double)3 * Dd * Hh * (Ww - 1));
        double mdy = gs[1] / ((double)3 * Dd * (Hh - 1) * Ww);
        double mdz = gs[2] / ((double)3 * (Dd - 1) * Hh * Ww);
        float smooth = (float)((mdx + mdy + mdz) / 3.0);
        out[0] = sim + smooth;
        out[1] = sim;
        out[2] = smooth;
    }
}

extern "C" void kernel_launch(void* const* d_in, const int* in_sizes, int n_in,
                              void* d_out, int out_size, void* d_ws, size_t ws_size,
                              hipStream_t stream) {
    const int*   fl = (const int*)d_in[0];
    const int*   ml = (const int*)d_in[1];
    const float* vf = (const float*)d_in[2];
    float* out = (float*)d_out;

    // workspace: [0, 3432) joint counts (858 uints); [3584, 3608) double sums[3]
    unsigned int* joint = (unsigned int*)d_ws;
    double*       sums  = (double*)((char*)d_ws + 3584);

    init_ws_kernel<<<1, 1024, 0, stream>>>(joint, sums);
    fused_kernel<<<FUSED_BLOCKS, TPB, 0, stream>>>(
        (const int4*)fl, (const int4*)ml, joint, (const float4*)vf, sums);
    finalize_kernel<<<1, 64, 0, stream>>>(joint, sums, out);
}